// Round 1
// baseline (724.190 us; speedup 1.0000x reference)
//
#include <hip/hip_runtime.h>
#include <stdint.h>

typedef __bf16 bf16x8 __attribute__((ext_vector_type(8)));
typedef float f32x4 __attribute__((ext_vector_type(4)));

#define AS1C(p) ((const __attribute__((address_space(1))) void*)(p))
#define AS3(p)  ((__attribute__((address_space(3))) void*)(p))

__device__ __forceinline__ unsigned short f2bf(float f) {
    unsigned int u = __float_as_uint(f);
    u += 0x7FFFu + ((u >> 16) & 1u);   // round-to-nearest-even
    return (unsigned short)(u >> 16);
}
__device__ __forceinline__ float leaky(float v) { return v > 0.0f ? v : 0.01f * v; }

// ---------------- weight convert + transpose: in[K][N] f32 -> out[N][K] bf16 --------
__global__ void k_transpose_bf16(const float* __restrict__ in, unsigned short* __restrict__ out,
                                 int K, int N) {
    int idx = blockIdx.x * 256 + threadIdx.x;
    if (idx >= K * N) return;
    int n = idx / K;
    int k = idx - n * K;
    out[idx] = f2bf(in[(size_t)k * N + n]);
}

// ---------------- feature encoder: feats[rows][896] bf16 ----------------
// layout: [0,256) src point enc (sin x, cos x, sin y, cos y ; 64 each)
//         [256,512) dst point enc, [512,640) t, [640,768) wait_src, [768,896) wait_dst
__global__ void k_encode(
    const float* __restrict__ src_xy, const float* __restrict__ dst_xy,
    const float* __restrict__ time_s, const float* __restrict__ wait_src, const float* __restrict__ wait_dst,
    const float* __restrict__ s_wsx, const float* __restrict__ s_bsx,
    const float* __restrict__ s_wcx, const float* __restrict__ s_bcx,
    const float* __restrict__ s_wsy, const float* __restrict__ s_bsy,
    const float* __restrict__ s_wcy, const float* __restrict__ s_bcy,
    const float* __restrict__ d_wsx, const float* __restrict__ d_bsx,
    const float* __restrict__ d_wcx, const float* __restrict__ d_bcx,
    const float* __restrict__ d_wsy, const float* __restrict__ d_bsy,
    const float* __restrict__ d_wcy, const float* __restrict__ d_bcy,
    const float* __restrict__ t_w, const float* __restrict__ t_b,
    const float* __restrict__ ws_w, const float* __restrict__ ws_b,
    const float* __restrict__ wd_w, const float* __restrict__ wd_b,
    unsigned short* __restrict__ out, int rows) {
    unsigned int g = blockIdx.x * 256u + threadIdx.x;
    if (g >= (unsigned)rows * 112u) return;
    unsigned int row = g / 112u;
    int k0 = (int)(g - row * 112u) * 8;

    float v[8];
    if (k0 < 512) {
        const float* xy = (k0 < 256) ? src_xy : dst_xy;
        int local = k0 & 255;
        int seg = local >> 6;      // 0: sin x, 1: cos x, 2: sin y, 3: cos y
        int j = local & 63;
        float sc = (seg < 2) ? xy[2 * row] : xy[2 * row + 1];
        const float* W;
        const float* Bv;
        if (k0 < 256) {
            W  = (seg == 0) ? s_wsx : (seg == 1) ? s_wcx : (seg == 2) ? s_wsy : s_wcy;
            Bv = (seg == 0) ? s_bsx : (seg == 1) ? s_bcx : (seg == 2) ? s_bsy : s_bcy;
        } else {
            W  = (seg == 0) ? d_wsx : (seg == 1) ? d_wcx : (seg == 2) ? d_wsy : d_wcy;
            Bv = (seg == 0) ? d_bsx : (seg == 1) ? d_bcx : (seg == 2) ? d_bsy : d_bcy;
        }
        bool isSin = ((seg & 1) == 0);
        float4 w0 = *(const float4*)&W[j],  w1 = *(const float4*)&W[j + 4];
        float4 b0 = *(const float4*)&Bv[j], b1v = *(const float4*)&Bv[j + 4];
        float wa[8] = {w0.x, w0.y, w0.z, w0.w, w1.x, w1.y, w1.z, w1.w};
        float ba[8] = {b0.x, b0.y, b0.z, b0.w, b1v.x, b1v.y, b1v.z, b1v.w};
#pragma unroll
        for (int i = 0; i < 8; ++i) {
            float a = fmaf(sc, wa[i], ba[i]);
            v[i] = isSin ? __sinf(a) : __cosf(a);
        }
    } else {
        int local = k0 - 512;
        int which = local >> 7;    // 0: t, 1: wait_src, 2: wait_dst
        int j = local & 127;
        float s = (which == 0) ? time_s[row] : (which == 1) ? wait_src[row] : wait_dst[row];
        const float* W  = (which == 0) ? t_w : (which == 1) ? ws_w : wd_w;
        const float* Bv = (which == 0) ? t_b : (which == 1) ? ws_b : wd_b;
        float4 w0 = *(const float4*)&W[j],  w1 = *(const float4*)&W[j + 4];
        float4 b0 = *(const float4*)&Bv[j], b1v = *(const float4*)&Bv[j + 4];
        float wa[8] = {w0.x, w0.y, w0.z, w0.w, w1.x, w1.y, w1.z, w1.w};
        float ba[8] = {b0.x, b0.y, b0.z, b0.w, b1v.x, b1v.y, b1v.z, b1v.w};
#pragma unroll
        for (int i = 0; i < 8; ++i) {
            float a = fmaf(s, wa[i], ba[i]);
            v[i] = leaky(a);
        }
    }
    unsigned int p0 = (unsigned)f2bf(v[0]) | ((unsigned)f2bf(v[1]) << 16);
    unsigned int p1 = (unsigned)f2bf(v[2]) | ((unsigned)f2bf(v[3]) << 16);
    unsigned int p2 = (unsigned)f2bf(v[4]) | ((unsigned)f2bf(v[5]) << 16);
    unsigned int p3 = (unsigned)f2bf(v[6]) | ((unsigned)f2bf(v[7]) << 16);
    uint4 pk = {p0, p1, p2, p3};
    *reinterpret_cast<uint4*>(out + (size_t)row * 896u + (unsigned)k0) = pk;
}

// ---------------- GEMM: C[M][512] = leaky(A[M][K] @ BT[512][K]^T + bias) ----------------
// m97 structure: 128x128 tile, BK=64, 4 waves, each wave 64x64 (4x4 frags of 16x16x32).
template <int K, bool OUT_BF16>
__global__ void k_gemm(const unsigned short* __restrict__ A, const unsigned short* __restrict__ BT,
                       const float* __restrict__ bias, void* __restrict__ Cv) {
    __shared__ __align__(16) unsigned short lA[128 * 64];
    __shared__ __align__(16) unsigned short lB[128 * 64];

    const int tid = threadIdx.x;

    // m204 bijective XCD swizzle; logical order = 4 consecutive N-tiles per M-tile.
    int nwg = gridDim.x, bid = blockIdx.x;
    int q = nwg >> 3, r = nwg & 7;
    int xcd = bid & 7, idx = bid >> 3;
    int swz = (xcd < r ? xcd * (q + 1) : r * (q + 1) + (xcd - r) * q) + idx;
    int mblk = swz >> 2, nblk = swz & 3;
    size_t brow = (size_t)mblk * 128;
    int bcol = nblk * 128;

    const int lane = tid & 63, w = tid >> 6;
    const int wr = w >> 1, wc = w & 1;
    const int lrow = lane & 15, kg = lane >> 4;

    f32x4 acc[4][4] = {};

    for (int kt = 0; kt < K / 64; ++kt) {
#pragma unroll
        for (int i = 0; i < 4; ++i) {
            int chunk = i * 256 + tid;          // 0..1023, 16B each
            int rr = chunk >> 3, cc = chunk & 7;
            __builtin_amdgcn_global_load_lds(AS1C(A + (brow + rr) * K + kt * 64 + cc * 8),
                                             AS3(lA + chunk * 8), 16, 0, 0);
            __builtin_amdgcn_global_load_lds(AS1C(BT + (size_t)(bcol + rr) * K + kt * 64 + cc * 8),
                                             AS3(lB + chunk * 8), 16, 0, 0);
        }
        __syncthreads();   // compiler drains vmcnt before barrier
#pragma unroll
        for (int kk = 0; kk < 2; ++kk) {
            bf16x8 af[4], bfr[4];
#pragma unroll
            for (int m = 0; m < 4; ++m)
                af[m] = *(const bf16x8*)&lA[(wr * 64 + m * 16 + lrow) * 64 + kk * 32 + kg * 8];
#pragma unroll
            for (int n = 0; n < 4; ++n)
                bfr[n] = *(const bf16x8*)&lB[(wc * 64 + n * 16 + lrow) * 64 + kk * 32 + kg * 8];
#pragma unroll
            for (int m = 0; m < 4; ++m)
#pragma unroll
                for (int n = 0; n < 4; ++n)
                    acc[m][n] = __builtin_amdgcn_mfma_f32_16x16x32_bf16(af[m], bfr[n], acc[m][n], 0, 0, 0);
        }
        __syncthreads();
    }

    // epilogue: bias + leaky, C/D layout col=lane&15, row=(lane>>4)*4+reg
#pragma unroll
    for (int n = 0; n < 4; ++n) {
        int col = bcol + wc * 64 + n * 16 + lrow;
        float bn = bias[col];
#pragma unroll
        for (int m = 0; m < 4; ++m) {
            size_t row0 = brow + wr * 64 + m * 16 + kg * 4;
#pragma unroll
            for (int rg = 0; rg < 4; ++rg) {
                float vv = leaky(acc[m][n][rg] + bn);
                if (OUT_BF16)
                    ((unsigned short*)Cv)[(row0 + rg) * 512 + col] = f2bf(vv);
                else
                    ((float*)Cv)[(row0 + rg) * 512 + col] = vv;
            }
        }
    }
}

extern "C" void kernel_launch(void* const* d_in, const int* in_sizes, int n_in,
                              void* d_out, int out_size, void* d_ws, size_t ws_size,
                              hipStream_t stream) {
    const float* src_xy   = (const float*)d_in[0];
    const float* dst_xy   = (const float*)d_in[1];
    const float* time_s   = (const float*)d_in[2];
    const float* wait_src = (const float*)d_in[3];
    const float* wait_dst = (const float*)d_in[4];
    const float* sp[8]; for (int i = 0; i < 8; ++i) sp[i] = (const float*)d_in[5 + i];
    const float* dp[8]; for (int i = 0; i < 8; ++i) dp[i] = (const float*)d_in[13 + i];
    const float* t_w  = (const float*)d_in[21];
    const float* t_b  = (const float*)d_in[22];
    const float* ws_w = (const float*)d_in[23];
    const float* ws_b = (const float*)d_in[24];
    const float* wd_w = (const float*)d_in[25];
    const float* wd_b = (const float*)d_in[26];
    const float* W1 = (const float*)d_in[27];
    const float* b1 = (const float*)d_in[28];
    const float* W2 = (const float*)d_in[29];
    const float* b2 = (const float*)d_in[30];

    unsigned short* W1T = (unsigned short*)d_ws;                       // 512*896 bf16
    unsigned short* W2T = (unsigned short*)((char*)d_ws + 917504);     // 512*512 bf16
    char* dyn = (char*)d_ws + 1441792;

    k_transpose_bf16<<<(896 * 512 + 255) / 256, 256, 0, stream>>>(W1, W1T, 896, 512);
    k_transpose_bf16<<<(512 * 512 + 255) / 256, 256, 0, stream>>>(W2, W2T, 512, 512);

    const int ROWS = 131072;
    size_t avail = ws_size > 1441792 ? ws_size - 1441792 : 0;
    int chunk = ROWS;                                    // bytes/row: 896*2 + 512*2 = 2816
    while (chunk > 128 && (size_t)chunk * 2816 > avail) chunk >>= 1;

    for (int r0 = 0; r0 < ROWS; r0 += chunk) {
        unsigned short* feats = (unsigned short*)dyn;                        // [chunk][896]
        unsigned short* h = (unsigned short*)(dyn + (size_t)chunk * 1792);   // [chunk][512]
        k_encode<<<(chunk * 112 + 255) / 256, 256, 0, stream>>>(
            src_xy + (size_t)r0 * 2, dst_xy + (size_t)r0 * 2,
            time_s + r0, wait_src + r0, wait_dst + r0,
            sp[0], sp[1], sp[2], sp[3], sp[4], sp[5], sp[6], sp[7],
            dp[0], dp[1], dp[2], dp[3], dp[4], dp[5], dp[6], dp[7],
            t_w, t_b, ws_w, ws_b, wd_w, wd_b, feats, chunk);
        k_gemm<896, true><<<(chunk / 128) * 4, 256, 0, stream>>>(feats, W1T, b1, (void*)h);
        k_gemm<512, false><<<(chunk / 128) * 4, 256, 0, stream>>>(h, W2T, b2,
                                                                  (void*)((float*)d_out + (size_t)r0 * 512));
    }
}